// Round 8
// baseline (839.236 us; speedup 1.0000x reference)
//
#include <hip/hip_runtime.h>
#include <hip/hip_fp16.h>

typedef unsigned int u32;

static inline size_t al16(size_t x){ return (x + 15) & ~(size_t)15; }

#define NPB 1024           // nodes per bucket
#define PBSH 10
#define NBLK 512           // partition blocks: run len = E/(NBLK*NB) ~ 64 edges
#define SRCMSK 0xFFFFFu

// A1: per-block LDS histogram of dst buckets. hist layout [blk][bucket].
__global__ void k_hist(const int* __restrict__ col, u32* __restrict__ hist,
                       int E, int NB, int chunk) {
  __shared__ u32 h[128];
  int tid = threadIdx.x, blk = blockIdx.x;
  if (tid < 128) h[tid] = 0;
  __syncthreads();
  int e0 = blk * chunk, e1 = min(E, e0 + chunk);
  for (int e = e0 + tid; e < e1; e += 256) atomicAdd(&h[col[e] >> PBSH], 1u);
  __syncthreads();
  for (int i = tid; i < NB; i += 256) hist[(size_t)blk * NB + i] = h[i];
}

// A2a: per-bucket exclusive scan over blocks -> hofs[bucket][blk]; totals.
__global__ void k_cscan(const u32* __restrict__ hist, u32* __restrict__ hofs,
                        u32* __restrict__ totals, int NB, int nblk) {
  __shared__ u32 s[256];
  int i = blockIdx.x, t = threadIdx.x;
  int R = nblk >> 8;
  u32 v[4]; u32 tsum = 0;
  for (int r = 0; r < R; r++) { v[r] = hist[(size_t)(t * R + r) * NB + i]; tsum += v[r]; }
  s[t] = tsum; __syncthreads();
  for (int off = 1; off < 256; off <<= 1) {
    u32 x = (t >= off) ? s[t - off] : 0u;
    __syncthreads(); s[t] += x; __syncthreads();
  }
  u32 run = s[t] - tsum;
  u32* hb = &hofs[(size_t)i * nblk + t * R];
  for (int r = 0; r < R; r++) { hb[r] = run; run += v[r]; }
  if (t == 255) totals[i] = s[255];
}

// A2b: scan bucket totals -> bstart.
__global__ void k_bscan(const u32* __restrict__ totals, u32* __restrict__ bstart,
                        int NB, int E) {
  __shared__ u32 s[128];
  int t = threadIdx.x;
  u32 v = (t < NB) ? totals[t] : 0u;
  s[t] = v; __syncthreads();
  for (int off = 1; off < 128; off <<= 1) {
    u32 x = (t >= off) ? s[t - off] : 0u;
    __syncthreads(); s[t] += x; __syncthreads();
  }
  if (t < NB) bstart[t] = s[t] - v;
  if (t == 0) bstart[NB] = (u32)E;
}

// A3: scatter edges into bucket-contiguous records {src|dl<<20, w}. No global atomics.
__global__ void k_part(const int* __restrict__ row, const int* __restrict__ col,
                       const float* __restrict__ ew, const u32* __restrict__ bstart,
                       const u32* __restrict__ hofs, uint2* __restrict__ recs,
                       int E, int NB, int nblk, int chunk) {
  __shared__ u32 cur[128];
  int tid = threadIdx.x, blk = blockIdx.x;
  if (tid < NB) cur[tid] = bstart[tid] + hofs[(size_t)tid * nblk + blk];
  __syncthreads();
  int e0 = blk * chunk, e1 = min(E, e0 + chunk);
  for (int e = e0 + tid; e < e1; e += 256) {
    int c = col[e];
    int b = c >> PBSH;
    u32 dl = (u32)(c & (NPB - 1));
    u32 pos = atomicAdd(&cur[b], 1u);
    uint2 v; v.x = (u32)row[e] | (dl << 20); v.y = __float_as_uint(ew[e]);
    recs[pos] = v;
  }
}

// B: weighted in-degree per bucket (LDS f32 atomics) -> dinv. No scans, no CSR.
__global__ void k_deg(const uint2* __restrict__ recs, const u32* __restrict__ bstart,
                      float* __restrict__ dinv, int N) {
  __shared__ float sdeg[NPB];
  int b = blockIdx.x, t = threadIdx.x;
  sdeg[t] = 0.f;
  __syncthreads();
  u32 r0 = bstart[b], r1 = bstart[b + 1];
  for (u32 e = r0 + t; e < r1; e += NPB) {
    uint2 v = recs[e];
    atomicAdd(&sdeg[v.x >> 20], __uint_as_float(v.y));
  }
  __syncthreads();
  int node = (b << PBSH) + t;
  if (node < N) dinv[node] = rsqrtf(sdeg[t] + 1.0f);  // +1 = self-loop
}

// Pre-scale edge weights by dinv[src] (streaming; dinv is L2-resident).
__global__ void k_scale(uint2* __restrict__ recs, const float* __restrict__ dinv, int E) {
  int stride = gridDim.x * blockDim.x;
  for (int e = blockIdx.x * blockDim.x + threadIdx.x; e < E; e += stride) {
    uint2 v = recs[e];
    v.y = __float_as_uint(dinv[v.x & SRCMSK] * __uint_as_float(v.y));
    recs[e] = v;
  }
}

// ht1 = x @ W1, fp16 CHUNK-MAJOR: ht1_chunks[s][node][4ch] (uint2 per node per chunk).
__global__ void k_gemm1(const float* __restrict__ x, const float* __restrict__ W1,
                        __half* __restrict__ ht1, int n) {
  __shared__ float sw[2048];
  for (int i = threadIdx.x; i < 2048; i += blockDim.x) sw[i] = W1[i];
  __syncthreads();
  int node = blockIdx.x * blockDim.x + threadIdx.x;
  if (node >= n) return;
  const float4* xr = (const float4*)(x + (size_t)node * 128);
  float acc[16];
  #pragma unroll
  for (int j = 0; j < 16; j++) acc[j] = 0.f;
  #pragma unroll 4
  for (int k4 = 0; k4 < 32; k4++) {
    float4 xv = xr[k4];
    const float* wb = &sw[k4 * 64];
    #pragma unroll
    for (int j = 0; j < 16; j++) acc[j] += xv.x * wb[j];
    #pragma unroll
    for (int j = 0; j < 16; j++) acc[j] += xv.y * wb[16 + j];
    #pragma unroll
    for (int j = 0; j < 16; j++) acc[j] += xv.z * wb[32 + j];
    #pragma unroll
    for (int j = 0; j < 16; j++) acc[j] += xv.w * wb[48 + j];
  }
  uint2* o = (uint2*)ht1;
  #pragma unroll
  for (int s = 0; s < 4; s++) {
    __half2 p0 = __floats2half2_rn(acc[4 * s + 0], acc[4 * s + 1]);
    __half2 p1 = __floats2half2_rn(acc[4 * s + 2], acc[4 * s + 3]);
    uint2 st; st.x = *(u32*)&p0; st.y = *(u32*)&p1;
    o[(size_t)s * n + node] = st;
  }
}

// Decode XCD-grouped block index: the 4 chunk-blocks of a bucket share (blockIdx&7),
// so they land on the same XCD and share its L2 copy of the bucket's recs.
__device__ __forceinline__ bool decode_bs(int NB, int& b, int& s) {
  int g8 = blockIdx.x >> 3, xcd = blockIdx.x & 7;
  s = g8 & 3;
  b = ((g8 >> 2) << 3) + xcd;
  return b < NB;
}

// Conv1 agg via LDS accumulators + bias + relu -> h1r (fp16 chunk-major).
// One thread per edge; plane-major acc (bank = dl%32, ~2-way).
__global__ void k_agg1(const __half* __restrict__ ht1, const uint2* __restrict__ recs,
                       const u32* __restrict__ bstart, const float* __restrict__ dinv,
                       const float* __restrict__ b1, __half* __restrict__ h1r,
                       int N, int NB) {
  __shared__ float acc[4 * NPB];
  int b, s;
  if (!decode_bs(NB, b, s)) return;
  int t = threadIdx.x;
  #pragma unroll
  for (int i = 0; i < 4; i++) acc[i * NPB + t] = 0.f;
  __syncthreads();
  u32 r0 = bstart[b], r1 = bstart[b + 1];
  const uint2* htc = (const uint2*)ht1 + (size_t)s * N;
  for (u32 e = r0 + t; e < r1; e += NPB) {
    uint2 v = recs[e];
    u32 dl = v.x >> 20;
    float w = __uint_as_float(v.y);
    uint2 h = htc[v.x & SRCMSK];
    float2 lo = __half22float2(*(__half2*)&h.x);
    float2 hi = __half22float2(*(__half2*)&h.y);
    atomicAdd(&acc[0 * NPB + dl], w * lo.x);
    atomicAdd(&acc[1 * NPB + dl], w * lo.y);
    atomicAdd(&acc[2 * NPB + dl], w * hi.x);
    atomicAdd(&acc[3 * NPB + dl], w * hi.y);
  }
  __syncthreads();
  int node = (b << PBSH) + t;
  if (node < N) {
    float di = dinv[node];
    uint2 hs = htc[node];
    float2 lo = __half22float2(*(__half2*)&hs.x);
    float2 hi = __half22float2(*(__half2*)&hs.y);
    float v0 = fmaxf(di * (acc[0 * NPB + t] + di * lo.x) + b1[4 * s + 0], 0.f);
    float v1 = fmaxf(di * (acc[1 * NPB + t] + di * lo.y) + b1[4 * s + 1], 0.f);
    float v2 = fmaxf(di * (acc[2 * NPB + t] + di * hi.x) + b1[4 * s + 2], 0.f);
    float v3 = fmaxf(di * (acc[3 * NPB + t] + di * hi.y) + b1[4 * s + 3], 0.f);
    __half2 p0 = __floats2half2_rn(v0, v1), p1 = __floats2half2_rn(v2, v3);
    uint2 st; st.x = *(u32*)&p0; st.y = *(u32*)&p1;
    ((uint2*)h1r)[(size_t)s * N + node] = st;
  }
}

// Conv2 agg over h1r (W2/b2 folded into k_final by linearity) + mean-pool partials.
__global__ void k_agg2(const __half* __restrict__ h1r, const uint2* __restrict__ recs,
                       const u32* __restrict__ bstart, const float* __restrict__ dinv,
                       const int* __restrict__ batch, float* __restrict__ pooledr,
                       int N, int NB) {
  __shared__ float acc[4 * NPB];
  __shared__ int sbid[NPB];
  int b, s;
  if (!decode_bs(NB, b, s)) return;
  int t = threadIdx.x;
  #pragma unroll
  for (int i = 0; i < 4; i++) acc[i * NPB + t] = 0.f;
  __syncthreads();
  u32 r0 = bstart[b], r1 = bstart[b + 1];
  const uint2* htc = (const uint2*)h1r + (size_t)s * N;
  for (u32 e = r0 + t; e < r1; e += NPB) {
    uint2 v = recs[e];
    u32 dl = v.x >> 20;
    float w = __uint_as_float(v.y);
    uint2 h = htc[v.x & SRCMSK];
    float2 lo = __half22float2(*(__half2*)&h.x);
    float2 hi = __half22float2(*(__half2*)&h.y);
    atomicAdd(&acc[0 * NPB + dl], w * lo.x);
    atomicAdd(&acc[1 * NPB + dl], w * lo.y);
    atomicAdd(&acc[2 * NPB + dl], w * hi.x);
    atomicAdd(&acc[3 * NPB + dl], w * hi.y);
  }
  __syncthreads();
  int node = (b << PBSH) + t;
  float u0 = 0.f, u1 = 0.f, u2 = 0.f, u3 = 0.f;
  int myb = -1;
  if (node < N) {
    float di = dinv[node];
    uint2 hs = htc[node];
    float2 lo = __half22float2(*(__half2*)&hs.x);
    float2 hi = __half22float2(*(__half2*)&hs.y);
    u0 = di * (acc[0 * NPB + t] + di * lo.x);
    u1 = di * (acc[1 * NPB + t] + di * lo.y);
    u2 = di * (acc[2 * NPB + t] + di * hi.x);
    u3 = di * (acc[3 * NPB + t] + di * hi.y);
    myb = batch[node];
  }
  acc[0 * NPB + t] = u0; acc[1 * NPB + t] = u1;
  acc[2 * NPB + t] = u2; acc[3 * NPB + t] = u3;
  sbid[t] = myb;
  __syncthreads();
  if (node < N && (t == 0 || sbid[t - 1] != myb)) {
    float s0 = u0, s1 = u1, s2 = u2, s3 = u3;
    for (int tt = t + 1; tt < NPB && sbid[tt] == myb; tt++) {
      s0 += acc[0 * NPB + tt]; s1 += acc[1 * NPB + tt];
      s2 += acc[2 * NPB + tt]; s3 += acc[3 * NPB + tt];
    }
    float* pb = &pooledr[(size_t)myb * 16 + 4 * s];
    unsafeAtomicAdd(pb + 0, s0);
    unsafeAtomicAdd(pb + 1, s1);
    unsafeAtomicAdd(pb + 2, s2);
    unsafeAtomicAdd(pb + 3, s3);
  }
}

// Final: out[g] = mean(pooledr)@W2@fcW + b2@fcW + fcb, with W2/b2 folded via M[c].
__global__ void k_final(const float* __restrict__ pooledr, const int* __restrict__ batch,
                        const float* __restrict__ W2, const float* __restrict__ b2,
                        const float* __restrict__ fcW, const float* __restrict__ fcb,
                        float* __restrict__ out, int n, int G) {
  __shared__ float M[16];
  __shared__ float bsum;
  int t = threadIdx.x;
  if (t < 16) {
    float m = 0.f;
    for (int j = 0; j < 16; j++) m += W2[t * 16 + j] * fcW[j];
    M[t] = m;
  }
  if (t == 16) {
    float bs = 0.f;
    for (int j = 0; j < 16; j++) bs += b2[j] * fcW[j];
    bsum = bs;
  }
  __syncthreads();
  int g = blockIdx.x * blockDim.x + t;
  if (g >= G) return;
  int lo = 0, hi = n;
  while (lo < hi) { int m = (lo + hi) >> 1; if (batch[m] < g) lo = m + 1; else hi = m; }
  int lo2 = lo, hi2 = n;
  while (lo2 < hi2) { int m = (lo2 + hi2) >> 1; if (batch[m] < g + 1) lo2 = m + 1; else hi2 = m; }
  int cnt = lo2 - lo;
  if (cnt <= 0) { out[g] = fcb[0]; return; }
  float inv = 1.0f / (float)cnt;
  float ssum = 0.f;
  #pragma unroll
  for (int c = 0; c < 16; c++) ssum += pooledr[(size_t)g * 16 + c] * M[c];
  out[g] = ssum * inv + bsum + fcb[0];
}

extern "C" void kernel_launch(void* const* d_in, const int* in_sizes, int n_in,
                              void* d_out, int out_size, void* d_ws, size_t ws_size,
                              hipStream_t stream) {
  const float* x    = (const float*)d_in[0];
  const int*   ei   = (const int*)d_in[1];
  const float* ew   = (const float*)d_in[2];
  const int*   batch= (const int*)d_in[3];
  const float* W1   = (const float*)d_in[4];
  const float* b1   = (const float*)d_in[5];
  const float* W2   = (const float*)d_in[6];
  const float* b2   = (const float*)d_in[7];
  const float* fcW  = (const float*)d_in[8];
  const float* fcb  = (const float*)d_in[9];
  float* out = (float*)d_out;

  int N = in_sizes[3];
  int E = in_sizes[2];
  int G = out_size;
  const int* row = ei;     // edge_index[0] = source
  const int* col = ei + E; // edge_index[1] = target

  int NB = (N + NPB - 1) >> PBSH;   // 98 buckets of 1024 nodes
  int nblk = NBLK;
  int chunk = (E + nblk - 1) / nblk;

  char* w = (char*)d_ws;
  size_t off = 0;
  auto alloc = [&](size_t bytes) -> char* { char* p = w + off; off = al16(off + bytes); return p; };
  u32*    hist    = (u32*)   alloc((size_t)NB * nblk * 4);
  u32*    hofs    = (u32*)   alloc((size_t)NB * nblk * 4);
  u32*    totals  = (u32*)   alloc((size_t)NB * 4);
  u32*    bstart  = (u32*)   alloc(((size_t)NB + 1) * 4);
  float*  dinv    = (float*) alloc((size_t)N * 4);
  uint2*  recs    = (uint2*) alloc((size_t)E * 8);
  __half* ht1     = (__half*)alloc((size_t)N * 16 * 2);
  __half* h1r     = (__half*)alloc((size_t)N * 16 * 2);
  float*  pooledr = (float*) alloc((size_t)G * 16 * 4);
  (void)n_in; (void)ws_size;

  hipMemsetAsync(pooledr, 0, (size_t)G * 16 * 4, stream);

  int nb = (N + 255) / 256;
  int gb = (G + 255) / 256;
  int agrid = 8 * 4 * ((NB + 7) / 8);   // XCD-grouped (bucket, chunk) blocks

  k_hist <<<nblk, 256, 0, stream>>>(col, hist, E, NB, chunk);
  k_cscan<<<NB, 256, 0, stream>>>(hist, hofs, totals, NB, nblk);
  k_bscan<<<1, 128, 0, stream>>>(totals, bstart, NB, E);
  k_part <<<nblk, 256, 0, stream>>>(row, col, ew, bstart, hofs, recs, E, NB, nblk, chunk);
  k_deg  <<<NB, NPB, 0, stream>>>(recs, bstart, dinv, N);
  k_scale<<<2048, 256, 0, stream>>>(recs, dinv, E);
  k_gemm1<<<nb, 256, 0, stream>>>(x, W1, ht1, N);
  k_agg1 <<<agrid, NPB, 0, stream>>>(ht1, recs, bstart, dinv, b1, h1r, N, NB);
  k_agg2 <<<agrid, NPB, 0, stream>>>(h1r, recs, bstart, dinv, batch, pooledr, N, NB);
  k_final<<<gb, 256, 0, stream>>>(pooledr, batch, W2, b2, fcW, fcb, out, N, G);
}

// Round 9
// 222.129 us; speedup vs baseline: 3.7782x; 3.7782x over previous
//
#include <hip/hip_runtime.h>
#include <hip/hip_fp16.h>

typedef unsigned int u32;

static inline size_t al16(size_t x){ return (x + 15) & ~(size_t)15; }

#define NPB 128            // nodes per bucket
#define PBSH 7
#define NBLK 128           // partition blocks (1024 thr each): run len = E/(NBLK*NB) ~32 edges
#define SRCMSK 0xFFFFFu
#define STAGE_CAP 5120     // LDS staging capacity (edges) per bucket; avg ~4096

// A1: per-block LDS histogram of dst buckets. hist layout [blk][bucket] (contiguous writes).
__global__ void k_hist(const int* __restrict__ col, u32* __restrict__ hist,
                       int E, int NB, int chunk) {
  __shared__ u32 h[1024];
  int tid = threadIdx.x, blk = blockIdx.x;
  for (int i = tid; i < 1024; i += 1024) h[i] = 0;
  __syncthreads();
  int e0 = blk * chunk, e1 = min(E, e0 + chunk);
  for (int e = e0 + tid; e < e1; e += 1024) atomicAdd(&h[col[e] >> PBSH], 1u);
  __syncthreads();
  for (int i = tid; i < NB; i += 1024) hist[(size_t)blk * NB + i] = h[i];
}

// A2a: per-bucket exclusive scan over the NBLK blocks -> hofs[bucket][blk]; totals.
__global__ void k_cscan(const u32* __restrict__ hist, u32* __restrict__ hofs,
                        u32* __restrict__ totals, int NB) {
  __shared__ u32 s[NBLK];
  int i = blockIdx.x, t = threadIdx.x;
  u32 v = hist[(size_t)t * NB + i];
  s[t] = v; __syncthreads();
  for (int off = 1; off < NBLK; off <<= 1) {
    u32 x = (t >= off) ? s[t - off] : 0u;
    __syncthreads(); s[t] += x; __syncthreads();
  }
  hofs[(size_t)i * NBLK + t] = s[t] - v;
  if (t == NBLK - 1) totals[i] = s[t];
}

// A2b: scan bucket totals -> bstart; sentinels.
__global__ void k_bscan(const u32* __restrict__ totals, u32* __restrict__ bstart,
                        u32* __restrict__ rowptr, int NB, int N, int E) {
  __shared__ u32 s[1024];
  int t = threadIdx.x;
  u32 v = (t < NB) ? totals[t] : 0u;
  s[t] = v; __syncthreads();
  for (int off = 1; off < 1024; off <<= 1) {
    u32 x = (t >= off) ? s[t - off] : 0u;
    __syncthreads(); s[t] += x; __syncthreads();
  }
  if (t < NB) bstart[t] = s[t] - v;
  if (t == 0) { bstart[NB] = (u32)E; rowptr[N] = (u32)E; }
}

// A3: scatter edges into bucket-contiguous records {src|dl<<20, w}. LDS cursors only.
__global__ void k_part(const int* __restrict__ row, const int* __restrict__ col,
                       const float* __restrict__ ew, const u32* __restrict__ bstart,
                       const u32* __restrict__ hofs, uint2* __restrict__ recs,
                       int E, int NB, int chunk) {
  __shared__ u32 cur[1024];
  int tid = threadIdx.x, blk = blockIdx.x;
  for (int i = tid; i < NB; i += 1024)
    cur[i] = bstart[i] + hofs[(size_t)i * NBLK + blk];
  __syncthreads();
  int e0 = blk * chunk, e1 = min(E, e0 + chunk);
  for (int e = e0 + tid; e < e1; e += 1024) {
    int c = col[e];
    int b = c >> PBSH;
    u32 dl = (u32)(c & (NPB - 1));
    u32 pos = atomicAdd(&cur[b], 1u);
    uint2 v; v.x = (u32)row[e] | (dl << 20); v.y = __float_as_uint(ew[e]);
    recs[pos] = v;
  }
}

// B: one block per bucket. count -> scan -> LDS-staged dl-sort -> COALESCED csr
// write-out (+rowptr). No f32 atomics; no partial-line global scatters.
__global__ void k_build(const uint2* __restrict__ recs, const u32* __restrict__ bstart,
                        u32* __restrict__ rowptr, uint2* __restrict__ csr, int N) {
  __shared__ uint2 stage[STAGE_CAP];
  __shared__ u32 cnt[NPB];
  __shared__ u32 sc[NPB];
  __shared__ u32 cur[NPB];
  int b = blockIdx.x, t = threadIdx.x;
  if (t < NPB) cnt[t] = 0;
  __syncthreads();
  u32 r0 = bstart[b], r1 = bstart[b + 1];
  int cap_ok = (r1 - r0) <= STAGE_CAP;
  for (u32 e = r0 + t; e < r1; e += 256) atomicAdd(&cnt[recs[e].x >> 20], 1u);
  __syncthreads();
  if (t < NPB) sc[t] = cnt[t];
  __syncthreads();
  for (int off = 1; off < NPB; off <<= 1) {
    u32 x = (t < NPB && t >= off) ? sc[t - off] : 0u;
    __syncthreads();
    if (t < NPB) sc[t] += x;
    __syncthreads();
  }
  if (t < NPB) {
    u32 excl = sc[t] - cnt[t];
    int node = (b << PBSH) + t;
    if (node < N) rowptr[node] = r0 + excl;
    cur[t] = excl;
  }
  __syncthreads();
  if (cap_ok) {
    for (u32 e = r0 + t; e < r1; e += 256) {
      uint2 v = recs[e];
      u32 dl = v.x >> 20;
      u32 slot = atomicAdd(&cur[dl], 1u);
      uint2 o; o.x = v.x & SRCMSK; o.y = v.y;
      stage[slot] = o;
    }
    __syncthreads();
    for (u32 i = t; i < r1 - r0; i += 256) csr[r0 + i] = stage[i];
  } else {
    // statistically-never fallback: direct scatter
    for (u32 e = r0 + t; e < r1; e += 256) {
      uint2 v = recs[e];
      u32 dl = v.x >> 20;
      u32 slot = atomicAdd(&cur[dl], 1u);
      uint2 o; o.x = v.x & SRCMSK; o.y = v.y;
      csr[r0 + slot] = o;
    }
  }
}

// Weighted in-degree from CSR rows (sequential reads, shuffle reduce) -> dinv.
__global__ void k_deg(const uint2* __restrict__ csr, const u32* __restrict__ rowptr,
                      float* __restrict__ dinv, int n) {
  int tid = threadIdx.x;
  int g = tid >> 4, j = tid & 15;
  int node = blockIdx.x * 16 + g;
  if (node >= n) return;
  u32 e0 = rowptr[node], e1 = rowptr[node + 1];
  float s = 0.f;
  for (u32 e = e0 + j; e < e1; e += 16) s += __uint_as_float(csr[e].y);
  #pragma unroll
  for (int off = 8; off; off >>= 1) s += __shfl_down(s, off, 16);
  if (j == 0) dinv[node] = rsqrtf(s + 1.0f);  // +1 = self-loop weight
}

// Pre-scale csr weights by dinv[src] (streaming RMW; dinv gather is L2-hot).
__global__ void k_scale(uint2* __restrict__ csr, const float* __restrict__ dinv, int E) {
  int stride = gridDim.x * blockDim.x;
  for (int e = blockIdx.x * blockDim.x + threadIdx.x; e < E; e += stride) {
    uint2 v = csr[e];
    v.y = __float_as_uint(dinv[v.x] * __uint_as_float(v.y));
    csr[e] = v;
  }
}

// ht1 = x @ W1, output fp16 node-major (table L2-resident: 3.2MB).
__global__ void k_gemm1(const float* __restrict__ x, const float* __restrict__ W1,
                        __half* __restrict__ ht1, int n) {
  __shared__ float sw[2048];
  for (int i = threadIdx.x; i < 2048; i += blockDim.x) sw[i] = W1[i];
  __syncthreads();
  int node = blockIdx.x * blockDim.x + threadIdx.x;
  if (node >= n) return;
  const float4* xr = (const float4*)(x + (size_t)node * 128);
  float acc[16];
  #pragma unroll
  for (int j = 0; j < 16; j++) acc[j] = 0.f;
  #pragma unroll 4
  for (int k4 = 0; k4 < 32; k4++) {
    float4 xv = xr[k4];
    const float* wb = &sw[k4 * 64];
    #pragma unroll
    for (int j = 0; j < 16; j++) acc[j] += xv.x * wb[j];
    #pragma unroll
    for (int j = 0; j < 16; j++) acc[j] += xv.y * wb[16 + j];
    #pragma unroll
    for (int j = 0; j < 16; j++) acc[j] += xv.z * wb[32 + j];
    #pragma unroll
    for (int j = 0; j < 16; j++) acc[j] += xv.w * wb[48 + j];
  }
  u32 o[8];
  #pragma unroll
  for (int p = 0; p < 8; p++) {
    u32 lo = (u32)__half_as_ushort(__float2half(acc[2 * p]));
    u32 hi = (u32)__half_as_ushort(__float2half(acc[2 * p + 1]));
    o[p] = lo | (hi << 16);
  }
  uint4* dst = (uint4*)(ht1 + (size_t)node * 16);
  dst[0] = make_uint4(o[0], o[1], o[2], o[3]);
  dst[1] = make_uint4(o[4], o[5], o[6], o[7]);
}

// Per-edge core: lane s owns channels 4s..4s+3; weights pre-scaled by dinv[src].
__device__ __forceinline__ void edge_sum4(const __half* __restrict__ ht,
                                          const uint2* __restrict__ csr,
                                          u32 e0, u32 e1, int s,
                                          float& a0, float& a1, float& a2, float& a3) {
  u32 e = e0;
  for (; e + 8 <= e1; e += 8) {
    uint2 v[8];
    #pragma unroll
    for (int t = 0; t < 8; t++) v[t] = csr[e + t];
    uint2 h[8];
    #pragma unroll
    for (int t = 0; t < 8; t++)
      h[t] = *(const uint2*)(ht + (size_t)v[t].x * 16 + s * 4);
    #pragma unroll
    for (int t = 0; t < 8; t++) {
      float w = __uint_as_float(v[t].y);
      float2 lo = __half22float2(*(__half2*)&h[t].x);
      float2 hi = __half22float2(*(__half2*)&h[t].y);
      a0 += w * lo.x; a1 += w * lo.y; a2 += w * hi.x; a3 += w * hi.y;
    }
  }
  for (; e < e1; e++) {
    uint2 v = csr[e];
    uint2 h = *(const uint2*)(ht + (size_t)v.x * 16 + s * 4);
    float w = __uint_as_float(v.y);
    float2 lo = __half22float2(*(__half2*)&h.x);
    float2 hi = __half22float2(*(__half2*)&h.y);
    a0 += w * lo.x; a1 += w * lo.y; a2 += w * hi.x; a3 += w * hi.y;
  }
}

// Conv1 agg + bias + relu, fused @W2. 4 lanes/node, 64 nodes/block.
__global__ void k_agg1(const __half* __restrict__ ht1, const u32* __restrict__ rowptr,
                       const uint2* __restrict__ csr, const float* __restrict__ dinv,
                       const float* __restrict__ b1, const float* __restrict__ W2,
                       __half* __restrict__ ht2, int n) {
  __shared__ float sw2[256];
  __shared__ float sr[64][20];
  int tid = threadIdx.x;
  sw2[tid] = W2[tid];
  int g = tid >> 2, s = tid & 3;
  int node = blockIdx.x * 64 + g;
  float a0 = 0.f, a1 = 0.f, a2 = 0.f, a3 = 0.f;
  if (node < n) {
    u32 e0 = rowptr[node], e1 = rowptr[node + 1];
    edge_sum4(ht1, csr, e0, e1, s, a0, a1, a2, a3);
    float di = dinv[node];
    uint2 hs = *(const uint2*)(ht1 + (size_t)node * 16 + s * 4);
    float2 slo = __half22float2(*(__half2*)&hs.x);
    float2 shi = __half22float2(*(__half2*)&hs.y);
    a0 = fmaxf(di * (a0 + di * slo.x) + b1[4 * s + 0], 0.f);
    a1 = fmaxf(di * (a1 + di * slo.y) + b1[4 * s + 1], 0.f);
    a2 = fmaxf(di * (a2 + di * shi.x) + b1[4 * s + 2], 0.f);
    a3 = fmaxf(di * (a3 + di * shi.y) + b1[4 * s + 3], 0.f);
  }
  *(float4*)&sr[g][4 * s] = make_float4(a0, a1, a2, a3);
  __syncthreads();
  if (node < n) {
    float o0 = 0.f, o1 = 0.f, o2 = 0.f, o3 = 0.f;
    #pragma unroll
    for (int k = 0; k < 16; k++) {
      float hk = sr[g][k];
      const float* wr = &sw2[k * 16 + 4 * s];
      o0 += hk * wr[0]; o1 += hk * wr[1]; o2 += hk * wr[2]; o3 += hk * wr[3];
    }
    __half2 p0 = __floats2half2_rn(o0, o1), p1 = __floats2half2_rn(o2, o3);
    uint2 st; st.x = *(u32*)&p0; st.y = *(u32*)&p1;
    *(uint2*)(ht2 + (size_t)node * 16 + 4 * s) = st;
  }
}

// Conv2 agg + bias, fused mean-pool partials (segmented LDS reduce + native f32 atomics).
__global__ void k_agg2(const __half* __restrict__ ht2, const u32* __restrict__ rowptr,
                       const uint2* __restrict__ csr, const float* __restrict__ dinv,
                       const float* __restrict__ b2, const int* __restrict__ batch,
                       float* __restrict__ pooled, int n) {
  __shared__ float sr[64][20];
  __shared__ int sbid[64];
  int tid = threadIdx.x;
  int g = tid >> 2, s = tid & 3;
  int node = blockIdx.x * 64 + g;
  float a0 = 0.f, a1 = 0.f, a2 = 0.f, a3 = 0.f;
  int myb = -1;
  if (node < n) {
    u32 e0 = rowptr[node], e1 = rowptr[node + 1];
    edge_sum4(ht2, csr, e0, e1, s, a0, a1, a2, a3);
    float di = dinv[node];
    uint2 hs = *(const uint2*)(ht2 + (size_t)node * 16 + s * 4);
    float2 slo = __half22float2(*(__half2*)&hs.x);
    float2 shi = __half22float2(*(__half2*)&hs.y);
    a0 = di * (a0 + di * slo.x) + b2[4 * s + 0];
    a1 = di * (a1 + di * slo.y) + b2[4 * s + 1];
    a2 = di * (a2 + di * shi.x) + b2[4 * s + 2];
    a3 = di * (a3 + di * shi.y) + b2[4 * s + 3];
    myb = batch[node];
  }
  *(float4*)&sr[g][4 * s] = make_float4(a0, a1, a2, a3);
  if (s == 0) sbid[g] = myb;
  __syncthreads();
  if (node < n) {
    bool head = (g == 0) || (sbid[g - 1] != myb);
    if (head) {
      float s0 = sr[g][4 * s + 0], s1 = sr[g][4 * s + 1];
      float s2 = sr[g][4 * s + 2], s3 = sr[g][4 * s + 3];
      for (int t = g + 1; t < 64 && sbid[t] == myb; t++) {
        s0 += sr[t][4 * s + 0]; s1 += sr[t][4 * s + 1];
        s2 += sr[t][4 * s + 2]; s3 += sr[t][4 * s + 3];
      }
      float* pb = &pooled[(size_t)myb * 16 + 4 * s];
      unsafeAtomicAdd(pb + 0, s0);
      unsafeAtomicAdd(pb + 1, s1);
      unsafeAtomicAdd(pb + 2, s2);
      unsafeAtomicAdd(pb + 3, s3);
    }
  }
}

// Mean + FC. Graph sizes via binary search on sorted batch.
__global__ void k_final(const float* __restrict__ pooled, const int* __restrict__ batch,
                        const float* __restrict__ fcW, const float* __restrict__ fcb,
                        float* __restrict__ out, int n, int G) {
  int g = blockIdx.x * blockDim.x + threadIdx.x;
  if (g >= G) return;
  int lo = 0, hi = n;
  while (lo < hi) { int m = (lo + hi) >> 1; if (batch[m] < g) lo = m + 1; else hi = m; }
  int lo2 = lo, hi2 = n;
  while (lo2 < hi2) { int m = (lo2 + hi2) >> 1; if (batch[m] < g + 1) lo2 = m + 1; else hi2 = m; }
  float c = (float)(lo2 - lo);
  float inv = 1.0f / fmaxf(c, 1.0f);
  float s = 0.f;
  #pragma unroll
  for (int j = 0; j < 16; j++) s += pooled[g * 16 + j] * fcW[j];
  out[g] = s * inv + fcb[0];
}

extern "C" void kernel_launch(void* const* d_in, const int* in_sizes, int n_in,
                              void* d_out, int out_size, void* d_ws, size_t ws_size,
                              hipStream_t stream) {
  const float* x    = (const float*)d_in[0];
  const int*   ei   = (const int*)d_in[1];
  const float* ew   = (const float*)d_in[2];
  const int*   batch= (const int*)d_in[3];
  const float* W1   = (const float*)d_in[4];
  const float* b1   = (const float*)d_in[5];
  const float* W2   = (const float*)d_in[6];
  const float* b2   = (const float*)d_in[7];
  const float* fcW  = (const float*)d_in[8];
  const float* fcb  = (const float*)d_in[9];
  float* out = (float*)d_out;

  int N = in_sizes[3];
  int E = in_sizes[2];
  int G = out_size;
  const int* row = ei;     // edge_index[0] = source
  const int* col = ei + E; // edge_index[1] = target

  int NB = (N + NPB - 1) >> PBSH;     // 128-node buckets (782 for N=100k)
  int chunk = (E + NBLK - 1) / NBLK;

  char* w = (char*)d_ws;
  size_t off = 0;
  auto alloc = [&](size_t bytes) -> char* { char* p = w + off; off = al16(off + bytes); return p; };
  u32*   hist   = (u32*)  alloc((size_t)NBLK * NB * 4);
  u32*   hofs   = (u32*)  alloc((size_t)NB * NBLK * 4);
  u32*   totals = (u32*)  alloc((size_t)NB * 4);
  u32*   bstart = (u32*)  alloc(((size_t)NB + 1) * 4);
  u32*   rowptr = (u32*)  alloc(((size_t)N + 1) * 4);
  float* dinv   = (float*)alloc((size_t)N * 4);
  uint2* recs   = (uint2*)alloc((size_t)E * 8);
  uint2* csr    = (uint2*)alloc((size_t)E * 8);
  float* pooled = (float*)alloc((size_t)G * 16 * 4);
  // recs dead after k_build: alias fp16 ht1/ht2 (gemm1 runs later).
  __half* ht1 = (__half*)recs;
  __half* ht2 = (__half*)((char*)recs + (size_t)N * 16 * 2);
  (void)n_in; (void)ws_size;

  hipMemsetAsync(pooled, 0, (size_t)G * 16 * 4, stream);

  int nb = (N + 255) / 256;
  int db = (N + 15) / 16;
  int ab = (N + 63) / 64;
  int gb = (G + 255) / 256;

  k_hist <<<NBLK, 1024, 0, stream>>>(col, hist, E, NB, chunk);
  k_cscan<<<NB, NBLK, 0, stream>>>(hist, hofs, totals, NB);
  k_bscan<<<1, 1024, 0, stream>>>(totals, bstart, rowptr, NB, N, E);
  k_part <<<NBLK, 1024, 0, stream>>>(row, col, ew, bstart, hofs, recs, E, NB, chunk);
  k_build<<<NB, 256, 0, stream>>>(recs, bstart, rowptr, csr, N);
  k_deg  <<<db, 256, 0, stream>>>(csr, rowptr, dinv, N);
  k_scale<<<2048, 256, 0, stream>>>(csr, dinv, E);
  k_gemm1<<<nb, 256, 0, stream>>>(x, W1, ht1, N);
  k_agg1 <<<ab, 256, 0, stream>>>(ht1, rowptr, csr, dinv, b1, W2, ht2, N);
  k_agg2 <<<ab, 256, 0, stream>>>(ht2, rowptr, csr, dinv, b2, batch, pooled, N);
  k_final<<<gb, 256, 0, stream>>>(pooled, batch, fcW, fcb, out, N, G);
}